// Round 17
// baseline (291.339 us; speedup 1.0000x reference)
//
#include <hip/hip_runtime.h>
#include <hip/hip_bf16.h>

// GIN forward, MI355X. Sizes fixed by the reference.
constexpr int N_NODES  = 100000;
constexpr int N_EDGES  = 1280000;
constexpr int HDIM     = 64;
constexpr int N_GRAPHS = 128;
constexpr int N_RES    = 4;
constexpr int CAP      = 64;       // CSR slots per node (P(deg>64) ~ e-60)
constexpr int ZNODE    = N_NODES;  // zero pad row index in padded h buffers

typedef __attribute__((ext_vector_type(8))) short bf16x8;
typedef __attribute__((ext_vector_type(4))) float f32x4;
typedef __attribute__((ext_vector_type(4))) int   i32x4;

// ---- bf16 helpers (RNE) ----
__device__ __forceinline__ unsigned f2bf1(float f) {
  unsigned u = __float_as_uint(f);
  return (u + 0x7fffu + ((u >> 16) & 1u)) >> 16;
}
__device__ __forceinline__ unsigned packbf(float lo, float hi) {
  return f2bf1(lo) | (f2bf1(hi) << 16);
}
__device__ __forceinline__ float bflo(unsigned u) { return __uint_as_float(u << 16); }
__device__ __forceinline__ float bfhi(unsigned u) { return __uint_as_float(u & 0xffff0000u); }
__device__ __forceinline__ float bf2f(unsigned short h) { return __uint_as_float(((unsigned)h) << 16); }

__device__ __forceinline__ float tanh_fast(float x) {
  float xc = fminf(fmaxf(x, -15.f), 15.f);
  float e = __expf(2.f * xc);
  return __fdividef(e - 1.f, e + 1.f);
}

// ---------------- CSR build: XCD-binned single pass ----------------
// R17: edge reads are NON-TEMPORAL. Range r's 128 blocks stream the whole
// 10.2MB edge array through XCD r's L2; with temporal loads that evicted the
// 3.2MB CSR window between the ~13 writes per node row -> 61.5MB HBM write
// dilution (R16 counter). NT loads keep the CSR scatter target resident.
constexpr int RNG = 8;
constexpr int RSZ = N_NODES / RNG;      // 12500
constexpr int CHUNKS = 128;
constexpr int CSZ = N_EDGES / CHUNKS;   // 10000

__global__ void fill_kernel(const int* __restrict__ ei,
                            int* __restrict__ cnt, int* __restrict__ csr) {
  int b = blockIdx.x;
  int lo = (b & (RNG - 1)) * RSZ;
  int hi = lo + RSZ;
  int base = (b >> 3) * CSZ;
  for (int i = base + threadIdx.x * 4; i < base + CSZ; i += 256 * 4) {
    i32x4 d4 = __builtin_nontemporal_load((const i32x4*)&ei[N_EDGES + i]);
    i32x4 s4 = __builtin_nontemporal_load((const i32x4*)&ei[i]);
    if (d4[0] >= lo && d4[0] < hi) { int p = atomicAdd(&cnt[d4[0]], 1); csr[d4[0] * CAP + (p & (CAP - 1))] = s4[0]; }
    if (d4[1] >= lo && d4[1] < hi) { int p = atomicAdd(&cnt[d4[1]], 1); csr[d4[1] * CAP + (p & (CAP - 1))] = s4[1]; }
    if (d4[2] >= lo && d4[2] < hi) { int p = atomicAdd(&cnt[d4[2]], 1); csr[d4[2] * CAP + (p & (CAP - 1))] = s4[2]; }
    if (d4[3] >= lo && d4[3] < hi) { int p = atomicAdd(&cnt[d4[3]], 1); csr[d4[3] * CAP + (p & (CAP - 1))] = s4[3]; }
  }
}

// ---------------- merged prep: prefill + cvt_pad + packw + goff ------------
__global__ void prep_kernel(const float* __restrict__ x, unsigned short* __restrict__ dstx,
                            int* __restrict__ csr,
                            const int* __restrict__ batch, int* __restrict__ goff,
                            const float* __restrict__ c1W1, const float* __restrict__ c1W2,
                            const float* __restrict__ csW1, const float* __restrict__ csW2,
                            unsigned short* __restrict__ wpk) {
  int i = blockIdx.x * 256 + threadIdx.x;

  // cvt_pad: x -> padded bf16 (grid-stride)
  constexpr int TOT = (N_NODES + 1) * HDIM / 2;
  constexpr int XN  = N_NODES * HDIM / 2;
  unsigned* d = (unsigned*)dstx;
  for (int k = i; k < TOT; k += 2048 * 256) {
    unsigned v = 0;
    if (k < XN) { float2 f = *(const float2*)&x[k * 2]; v = packbf(f.x, f.y); }
    d[k] = v;
  }

  // prefill: ZNODE sentinel in slots 0..15 of every CSR row
  if (i <= N_NODES) {
    int4 z4 = make_int4(ZNODE, ZNODE, ZNODE, ZNODE);
    int4* p = (int4*)(csr + (size_t)i * CAP);
    p[0] = z4; p[1] = z4; p[2] = z4; p[3] = z4;
  }

  // packw: B-fragment pack, hi|lo split. Layer l: W1 @ l*16384, W2 @ +8192.
  if (i < 10 * 4096) {
    int mat = i >> 12;
    int e   = i & 4095;
    int f    = e >> 9;
    int lane = (e >> 3) & 63;
    int ii   = e & 7;
    int tc = f >> 1, ks = f & 1;
    int krow = ks * 32 + (lane >> 4) * 8 + ii;
    int col  = tc * 16 + (lane & 15);
    int l = mat >> 1;
    const float* W;
    if (l == 0) W = (mat & 1) ? c1W2 : c1W1;
    else        W = ((mat & 1) ? csW2 : csW1) + (size_t)(l - 1) * 4096;
    float w = W[krow * 64 + col];
    unsigned short hi = (unsigned short)f2bf1(w);
    unsigned short lo = (unsigned short)f2bf1(w - bf2f(hi));
    unsigned short* dd = wpk + (size_t)mat * 8192;
    dd[e] = hi;
    dd[4096 + e] = lo;
  }

  // goff: lower_bound over sorted batch
  if (i <= N_GRAPHS) {
    int lo = 0, hi = N_NODES;
    while (lo < hi) {
      int mid = (lo + hi) >> 1;
      if (batch[mid] < i) lo = mid + 1; else hi = mid;
    }
    goff[i] = lo;
  }
}

// ---------------- fused GIN conv: R12-exact (empirical optimum) ------------
// 256 thr = 4 waves, 64 nodes. Gather: 8 sequential pair-passes, half-wave
// per node, lane = 2 features bf16x2 (whole-row coalesced loads), CSR slots
// s_load'ed, ZNODE sentinel. Concurrency-saturated (R13/R14/R15 all
// regressed): gather is memory-system (L3/fabric random-access) bound.
// z split bf16 hi/lo -> LDS [node][k] stride 72. MLP: per wave 16 nodes x 64
// feats via mfma_f32_16x16x32_bf16, 3-product split, W pre-packed B-frags.
template <bool RESID>
__global__ __launch_bounds__(256, 6)
void conv_kernel(const unsigned short* __restrict__ hin, unsigned short* __restrict__ hout,
                 const int* __restrict__ cnt, const int* __restrict__ csr,
                 const unsigned short* __restrict__ Wpk,   // layer: W1 hi|lo, W2 hi|lo
                 const float* __restrict__ b1, const float* __restrict__ b2,
                 const float* __restrict__ gam, const float* __restrict__ bet,
                 const float* __restrict__ rm, const float* __restrict__ rv) {
  __shared__ __align__(16) unsigned short zb0[64][72];   // hi
  __shared__ __align__(16) unsigned short zb1[64][72];   // lo
  const int t   = threadIdx.x;
  const int ln  = t & 63;
  const int wid = __builtin_amdgcn_readfirstlane(t >> 6);   // 0..3
  const int lc  = ln & 31;
  const bool hiH = ln >= 32;
  const int nb  = blockIdx.x * 64;
  const unsigned* hb = (const unsigned*)hin;   // row stride 32 words

  // ---- gather: wave wid -> local nodes [16*wid, 16*wid+16), 8 pairs ----
  for (int p = 0; p < 8; ++p) {
    int m = wid * 16 + 2 * p;
    int nA = nb + m; if (nA > ZNODE) nA = ZNODE;
    int nB = nA + 1; if (nB > ZNODE) nB = ZNODE;
    const int* rA = csr + (size_t)nA * CAP;
    const int* rB = csr + (size_t)nB * CAP;
    int4 a0 = *(const int4*)(rA + 0), a1q = *(const int4*)(rA + 4);
    int4 a2 = *(const int4*)(rA + 8), a3q = *(const int4*)(rA + 12);
    int4 b0 = *(const int4*)(rB + 0), b1q = *(const int4*)(rB + 4);
    int4 b2q = *(const int4*)(rB + 8), b3q = *(const int4*)(rB + 12);
    int dA = cnt[nA], dB = cnt[nB];

    int self = hiH ? nB : nA;
    float z0, z1;
    { unsigned u = hb[(size_t)self * 32 + lc]; z0 = bflo(u); z1 = bfhi(u); }
    int i0  = hiH ? b0.x  : a0.x;   int i1  = hiH ? b0.y  : a0.y;
    int i2  = hiH ? b0.z  : a0.z;   int i3  = hiH ? b0.w  : a0.w;
    int i4  = hiH ? b1q.x : a1q.x;  int i5  = hiH ? b1q.y : a1q.y;
    int i6  = hiH ? b1q.z : a1q.z;  int i7  = hiH ? b1q.w : a1q.w;
    int i8  = hiH ? b2q.x : a2.x;   int i9  = hiH ? b2q.y : a2.y;
    int i10 = hiH ? b2q.z : a2.z;   int i11 = hiH ? b2q.w : a2.w;
    int i12 = hiH ? b3q.x : a3q.x;  int i13 = hiH ? b3q.y : a3q.y;
    int i14 = hiH ? b3q.z : a3q.z;  int i15 = hiH ? b3q.w : a3q.w;
#define GACC(ix) { unsigned u = hb[(size_t)(ix) * 32 + lc]; z0 += bflo(u); z1 += bfhi(u); }
    GACC(i0)  GACC(i1)  GACC(i2)  GACC(i3)
    GACC(i4)  GACC(i5)  GACC(i6)  GACC(i7)
    GACC(i8)  GACC(i9)  GACC(i10) GACC(i11)
    GACC(i12) GACC(i13) GACC(i14) GACC(i15)
#undef GACC
    if (dA > 16 && !hiH)
      for (int q = 16; q < dA; ++q) { unsigned u = hb[(size_t)rA[q] * 32 + lc]; z0 += bflo(u); z1 += bfhi(u); }
    if (dB > 16 && hiH)
      for (int q = 16; q < dB; ++q) { unsigned u = hb[(size_t)rB[q] * 32 + lc]; z0 += bflo(u); z1 += bfhi(u); }
    int mr = m + (hiH ? 1 : 0);
    unsigned h0 = f2bf1(z0);
    float r0 = z0 - __uint_as_float(h0 << 16);
    float r1 = z1 - __uint_as_float(f2bf1(z1) << 16);
    *(unsigned*)&zb0[mr][2 * lc] = h0 | (f2bf1(z1) << 16);
    *(unsigned*)&zb1[mr][2 * lc] = f2bf1(r0) | (f2bf1(r1) << 16);
  }
  __syncthreads();    // fence: order gather LDS stores before b128 frag reads

  const int l15 = ln & 15, lg = ln >> 4;
  const int arow = 16 * wid + l15;                  // A-frag row (node-local)
  const unsigned short* W1pk = Wpk;
  const unsigned short* W2pk = Wpk + 8192;          // per-matrix block = 8192 bf16

  // ---- matvec 1: a1 = relu(z @ W1 + b1), wave-local 16 nodes x 64 feats ----
  f32x4 acc[4];
#pragma unroll
  for (int tc = 0; tc < 4; ++tc) {
    float bv = b1[tc * 16 + l15];
    acc[tc] = (f32x4){bv, bv, bv, bv};
  }
#pragma unroll
  for (int ks = 0; ks < 2; ++ks) {
    bf16x8 ah = *(const bf16x8*)&zb0[arow][lg * 8 + ks * 32];
    bf16x8 al = *(const bf16x8*)&zb1[arow][lg * 8 + ks * 32];
#pragma unroll
    for (int tc = 0; tc < 4; ++tc) {
      bf16x8 bh = *(const bf16x8*)&W1pk[(size_t)((tc * 2 + ks) * 64 + ln) * 8];
      bf16x8 bl = *(const bf16x8*)&W1pk[4096 + (size_t)((tc * 2 + ks) * 64 + ln) * 8];
      acc[tc] = __builtin_amdgcn_mfma_f32_16x16x32_bf16(ah, bh, acc[tc], 0, 0, 0);
      acc[tc] = __builtin_amdgcn_mfma_f32_16x16x32_bf16(al, bh, acc[tc], 0, 0, 0);
      acc[tc] = __builtin_amdgcn_mfma_f32_16x16x32_bf16(ah, bl, acc[tc], 0, 0, 0);
    }
  }
  __syncthreads();    // all matvec-1 A reads complete before a1 overwrite

  // ---- ReLU + split + write a1 back to zb (same wave-private rows) ----
#pragma unroll
  for (int tc = 0; tc < 4; ++tc) {
#pragma unroll
    for (int r = 0; r < 4; ++r) {
      float v = fmaxf(acc[tc][r], 0.0f);
      int node = 16 * wid + lg * 4 + r;
      int feat = tc * 16 + l15;
      unsigned short hh = (unsigned short)f2bf1(v);
      zb0[node][feat] = hh;
      zb1[node][feat] = (unsigned short)f2bf1(v - bf2f(hh));
    }
  }
  __syncthreads();    // fence: order a1 stores before matvec-2 frag reads

  // ---- matvec 2: y = a1 @ W2 + b2 ----
#pragma unroll
  for (int tc = 0; tc < 4; ++tc) {
    float bv = b2[tc * 16 + l15];
    acc[tc] = (f32x4){bv, bv, bv, bv};
  }
#pragma unroll
  for (int ks = 0; ks < 2; ++ks) {
    bf16x8 ah = *(const bf16x8*)&zb0[arow][lg * 8 + ks * 32];
    bf16x8 al = *(const bf16x8*)&zb1[arow][lg * 8 + ks * 32];
#pragma unroll
    for (int tc = 0; tc < 4; ++tc) {
      bf16x8 bh = *(const bf16x8*)&W2pk[(size_t)((tc * 2 + ks) * 64 + ln) * 8];
      bf16x8 bl = *(const bf16x8*)&W2pk[4096 + (size_t)((tc * 2 + ks) * 64 + ln) * 8];
      acc[tc] = __builtin_amdgcn_mfma_f32_16x16x32_bf16(ah, bh, acc[tc], 0, 0, 0);
      acc[tc] = __builtin_amdgcn_mfma_f32_16x16x32_bf16(al, bh, acc[tc], 0, 0, 0);
      acc[tc] = __builtin_amdgcn_mfma_f32_16x16x32_bf16(ah, bl, acc[tc], 0, 0, 0);
    }
  }

  // ---- ReLU + BN (+residual) + bf16 store ----
#pragma unroll
  for (int tc = 0; tc < 4; ++tc) {
    int feat = tc * 16 + l15;
    float sc = gam[feat] * rsqrtf(rv[feat] + 1e-5f);
    float sh = bet[feat] - rm[feat] * sc;
#pragma unroll
    for (int r = 0; r < 4; ++r) {
      int gn = nb + 16 * wid + lg * 4 + r;
      bool v = gn < N_NODES;
      int gnc = v ? gn : ZNODE;
      float y = fmaxf(acc[tc][r], 0.0f) * sc + sh;
      if (RESID) y += bf2f(hin[(size_t)gnc * 64 + feat]);
      if (v) hout[(size_t)gn * 64 + feat] = (unsigned short)f2bf1(y);
    }
  }
}

// ---------------- fused head + mean-pool partial sums (R9-proven) ----------
__global__ __launch_bounds__(512, 6)
void head_pool_kernel(const unsigned short* __restrict__ hin, float* __restrict__ out,
                      const int* __restrict__ batch,
                      const float* __restrict__ W, const float* __restrict__ b) {
  const int t   = threadIdx.x;
  const int ln  = t & 63;
  const int wid = __builtin_amdgcn_readfirstlane(t >> 6);
  const int n = blockIdx.x * 64 + ln;
  const bool valid = n < N_NODES;
  const int nn = valid ? n : ZNODE;
  const unsigned* hb = (const unsigned*)hin;

  unsigned zp[32];
#pragma unroll
  for (int cc = 0; cc < 8; ++cc) {
    uint4 u = *(const uint4*)&hb[(size_t)nn * 32 + cc * 4];
    zp[cc * 4 + 0] = u.x; zp[cc * 4 + 1] = u.y;
    zp[cc * 4 + 2] = u.z; zp[cc * 4 + 3] = u.w;
  }

  const float* Wp = W + wid * 8;
  const float* bp = b + wid * 8;
  float acc[8];
#pragma unroll
  for (int f = 0; f < 8; ++f) acc[f] = bp[f];
#pragma unroll
  for (int w = 0; w < 32; ++w) {
    float zlo = bflo(zp[w]), zhi = bfhi(zp[w]);
#pragma unroll
    for (int f = 0; f < 8; ++f) acc[f] = fmaf(zlo, Wp[(2 * w) * 64 + f], acc[f]);
#pragma unroll
    for (int f = 0; f < 8; ++f) acc[f] = fmaf(zhi, Wp[(2 * w + 1) * 64 + f], acc[f]);
  }
#pragma unroll
  for (int f = 0; f < 8; ++f) acc[f] = tanh_fast(acc[f]);

  int bg = valid ? batch[n] : -1;
  int gmax = bg;
#pragma unroll
  for (int off = 32; off >= 1; off >>= 1) gmax = max(gmax, __shfl_xor(gmax, off));
  gmax = __builtin_amdgcn_readfirstlane(gmax);
  int g0 = __builtin_amdgcn_readfirstlane(bg);

  for (int g = g0; g <= gmax; ++g) {
    float s[8];
    bool inG = (bg == g);
#pragma unroll
    for (int f = 0; f < 8; ++f) s[f] = inG ? acc[f] : 0.0f;
#pragma unroll
    for (int off = 1; off <= 32; off <<= 1) {
#pragma unroll
      for (int f = 0; f < 8; ++f) s[f] += __shfl_xor(s[f], off);
    }
    float sv = s[0];
    sv = (ln == 1) ? s[1] : sv;  sv = (ln == 2) ? s[2] : sv;
    sv = (ln == 3) ? s[3] : sv;  sv = (ln == 4) ? s[4] : sv;
    sv = (ln == 5) ? s[5] : sv;  sv = (ln == 6) ? s[6] : sv;
    sv = (ln == 7) ? s[7] : sv;
    if (ln < 8) atomicAdd(&out[g * 64 + wid * 8 + ln], sv);
  }
}

// out[g][f] /= max(count_g, 1)
__global__ void div_kernel(float* __restrict__ out, const int* __restrict__ goff) {
  int i = blockIdx.x * blockDim.x + threadIdx.x;
  if (i >= N_GRAPHS * 64) return;
  int g = i >> 6;
  int c = goff[g + 1] - goff[g];
  out[i] /= (float)max(c, 1);
}

// ---------------- launch ----------------
extern "C" void kernel_launch(void* const* d_in, const int* in_sizes, int n_in,
                              void* d_out, int out_size, void* d_ws, size_t ws_size,
                              hipStream_t stream) {
  const float* x     = (const float*)d_in[0];
  const int*   ei    = (const int*)d_in[1];
  const int*   batch = (const int*)d_in[2];
  const float* c1_W1 = (const float*)d_in[3];
  const float* c1_b1 = (const float*)d_in[4];
  const float* c1_W2 = (const float*)d_in[5];
  const float* c1_b2 = (const float*)d_in[6];
  const float* c1_g  = (const float*)d_in[7];
  const float* c1_be = (const float*)d_in[8];
  const float* c1_m  = (const float*)d_in[9];
  const float* c1_v  = (const float*)d_in[10];
  const float* cs_W1 = (const float*)d_in[11];
  const float* cs_b1 = (const float*)d_in[12];
  const float* cs_W2 = (const float*)d_in[13];
  const float* cs_b2 = (const float*)d_in[14];
  const float* cs_g  = (const float*)d_in[15];
  const float* cs_be = (const float*)d_in[16];
  const float* cs_m  = (const float*)d_in[17];
  const float* cs_v  = (const float*)d_in[18];
  const float* lin_W = (const float*)d_in[19];
  const float* lin_b = (const float*)d_in[20];
  float* out = (float*)d_out;

  size_t cur = 0;
  auto take = [&](size_t bytes) -> void* {
    void* p = (char*)d_ws + cur;
    cur += (bytes + 255) & ~(size_t)255;
    return p;
  };
  int* cnt  = (int*)take((N_NODES + 1) * sizeof(int));
  size_t zbytes = cur;                       // cnt zeroed every call
  int* goff = (int*)take((N_GRAPHS + 1) * sizeof(int));
  int* csr  = (int*)take((size_t)(N_NODES + 1) * CAP * sizeof(int));
  unsigned short* bufA = (unsigned short*)take((size_t)(N_NODES + 1) * HDIM * sizeof(unsigned short));
  unsigned short* bufB = (unsigned short*)take((size_t)(N_NODES + 1) * HDIM * sizeof(unsigned short));
  unsigned short* wpk  = (unsigned short*)take((size_t)10 * 8192 * sizeof(unsigned short));
  (void)ws_size; (void)in_sizes; (void)n_in; (void)out_size;

  hipMemsetAsync(cnt, 0, zbytes, stream);
  hipMemsetAsync(bufA + (size_t)ZNODE * HDIM, 0, HDIM * sizeof(unsigned short), stream);
  hipMemsetAsync(out, 0, N_GRAPHS * 64 * sizeof(float), stream);

  // merged prep (prefill + cvt_pad + packw + goff), then fill
  prep_kernel<<<2048, 256, 0, stream>>>(x, bufB, csr, batch, goff,
                                        c1_W1, c1_W2, cs_W1, cs_W2, wpk);
  fill_kernel<<<RNG * CHUNKS, 256, 0, stream>>>(ei, cnt, csr);

  const int NBLK = (N_NODES + 63) / 64;      // 1563 blocks x 256 thr (4 waves)

  // conv1: bufB(x) -> bufA  (layer l weight block at wpk + l*16384)
  conv_kernel<false><<<NBLK, 256, 0, stream>>>(bufB, bufA, cnt, csr,
      wpk, c1_b1, c1_b2, c1_g, c1_be, c1_m, c1_v);

  // 4 residual convs: A->B->A->B->A
  unsigned short* srcp = bufA;
  unsigned short* dstp = bufB;
  for (int l = 0; l < N_RES; ++l) {
    conv_kernel<true><<<NBLK, 256, 0, stream>>>(srcp, dstp, cnt, csr,
        wpk + (size_t)(l + 1) * 16384,
        cs_b1 + l * 64, cs_b2 + l * 64,
        cs_g + l * 64, cs_be + l * 64, cs_m + l * 64, cs_v + l * 64);
    unsigned short* tmp = srcp; srcp = dstp; dstp = tmp;
  }
  // final h in bufA (srcp); fused head + pool -> out, then divide by counts
  head_pool_kernel<<<NBLK, 512, 0, stream>>>(srcp, out, batch, lin_W, lin_b);
  div_kernel<<<(N_GRAPHS * 64 + 255) / 256, 256, 0, stream>>>(out, goff);
}

// Round 18
// 287.895 us; speedup vs baseline: 1.0120x; 1.0120x over previous
//
#include <hip/hip_runtime.h>
#include <hip/hip_bf16.h>

// GIN forward, MI355X. Sizes fixed by the reference.
constexpr int N_NODES  = 100000;
constexpr int N_EDGES  = 1280000;
constexpr int HDIM     = 64;
constexpr int N_GRAPHS = 128;
constexpr int N_RES    = 4;
constexpr int CAP      = 64;       // CSR slots per node (P(deg>64) ~ e-60)
constexpr int ZNODE    = N_NODES;  // zero pad row index in padded h buffers

typedef __attribute__((ext_vector_type(8))) short bf16x8;
typedef __attribute__((ext_vector_type(4))) float f32x4;

// ---- bf16 helpers (RNE) ----
__device__ __forceinline__ unsigned f2bf1(float f) {
  unsigned u = __float_as_uint(f);
  return (u + 0x7fffu + ((u >> 16) & 1u)) >> 16;
}
__device__ __forceinline__ unsigned packbf(float lo, float hi) {
  return f2bf1(lo) | (f2bf1(hi) << 16);
}
__device__ __forceinline__ float bflo(unsigned u) { return __uint_as_float(u << 16); }
__device__ __forceinline__ float bfhi(unsigned u) { return __uint_as_float(u & 0xffff0000u); }
__device__ __forceinline__ float bf2f(unsigned short h) { return __uint_as_float(((unsigned)h) << 16); }

__device__ __forceinline__ float tanh_fast(float x) {
  float xc = fminf(fmaxf(x, -15.f), 15.f);
  float e = __expf(2.f * xc);
  return __fdividef(e - 1.f, e + 1.f);
}

// ---------------- CSR build: XCD-binned single pass (R12/R16-proven) -------
// Write-dilution (~60MB HBM writes vs 6.4MB ideal) is structural: the ~13
// writes per CSR line span the kernel's whole duration; NT edge reads (R17)
// and atomic batching (R13) both failed to improve it.
constexpr int RNG = 8;
constexpr int RSZ = N_NODES / RNG;      // 12500
constexpr int CHUNKS = 128;
constexpr int CSZ = N_EDGES / CHUNKS;   // 10000

__global__ void fill_kernel(const int* __restrict__ ei,
                            int* __restrict__ cnt, int* __restrict__ csr) {
  int b = blockIdx.x;
  int lo = (b & (RNG - 1)) * RSZ;
  int hi = lo + RSZ;
  int base = (b >> 3) * CSZ;
  for (int i = base + threadIdx.x * 4; i < base + CSZ; i += 256 * 4) {
    int4 d4 = *(const int4*)&ei[N_EDGES + i];
    int4 s4 = *(const int4*)&ei[i];
    if (d4.x >= lo && d4.x < hi) { int p = atomicAdd(&cnt[d4.x], 1); csr[d4.x * CAP + (p & (CAP - 1))] = s4.x; }
    if (d4.y >= lo && d4.y < hi) { int p = atomicAdd(&cnt[d4.y], 1); csr[d4.y * CAP + (p & (CAP - 1))] = s4.y; }
    if (d4.z >= lo && d4.z < hi) { int p = atomicAdd(&cnt[d4.z], 1); csr[d4.z * CAP + (p & (CAP - 1))] = s4.z; }
    if (d4.w >= lo && d4.w < hi) { int p = atomicAdd(&cnt[d4.w], 1); csr[d4.w * CAP + (p & (CAP - 1))] = s4.w; }
  }
}

// ---------------- merged prep: prefill + cvt_pad + packw + goff ------------
__global__ void prep_kernel(const float* __restrict__ x, unsigned short* __restrict__ dstx,
                            int* __restrict__ csr,
                            const int* __restrict__ batch, int* __restrict__ goff,
                            const float* __restrict__ c1W1, const float* __restrict__ c1W2,
                            const float* __restrict__ csW1, const float* __restrict__ csW2,
                            unsigned short* __restrict__ wpk) {
  int i = blockIdx.x * 256 + threadIdx.x;

  // cvt_pad: x -> padded bf16 (grid-stride)
  constexpr int TOT = (N_NODES + 1) * HDIM / 2;
  constexpr int XN  = N_NODES * HDIM / 2;
  unsigned* d = (unsigned*)dstx;
  for (int k = i; k < TOT; k += 2048 * 256) {
    unsigned v = 0;
    if (k < XN) { float2 f = *(const float2*)&x[k * 2]; v = packbf(f.x, f.y); }
    d[k] = v;
  }

  // prefill: ZNODE sentinel in slots 0..15 of every CSR row
  if (i <= N_NODES) {
    int4 z4 = make_int4(ZNODE, ZNODE, ZNODE, ZNODE);
    int4* p = (int4*)(csr + (size_t)i * CAP);
    p[0] = z4; p[1] = z4; p[2] = z4; p[3] = z4;
  }

  // packw: B-fragment pack, hi|lo split. Layer l: W1 @ l*16384, W2 @ +8192.
  if (i < 10 * 4096) {
    int mat = i >> 12;
    int e   = i & 4095;
    int f    = e >> 9;
    int lane = (e >> 3) & 63;
    int ii   = e & 7;
    int tc = f >> 1, ks = f & 1;
    int krow = ks * 32 + (lane >> 4) * 8 + ii;
    int col  = tc * 16 + (lane & 15);
    int l = mat >> 1;
    const float* W;
    if (l == 0) W = (mat & 1) ? c1W2 : c1W1;
    else        W = ((mat & 1) ? csW2 : csW1) + (size_t)(l - 1) * 4096;
    float w = W[krow * 64 + col];
    unsigned short hi = (unsigned short)f2bf1(w);
    unsigned short lo = (unsigned short)f2bf1(w - bf2f(hi));
    unsigned short* dd = wpk + (size_t)mat * 8192;
    dd[e] = hi;
    dd[4096 + e] = lo;
  }

  // goff: lower_bound over sorted batch
  if (i <= N_GRAPHS) {
    int lo = 0, hi = N_NODES;
    while (lo < hi) {
      int mid = (lo + hi) >> 1;
      if (batch[mid] < i) lo = mid + 1; else hi = mid;
    }
    goff[i] = lo;
  }
}

// ---------------- fused GIN conv: R12-exact (empirical optimum) ------------
// 256 thr = 4 waves, 64 nodes. Gather: 8 sequential pair-passes, half-wave
// per node, lane = 2 features bf16x2 (whole-row coalesced loads), CSR slots
// s_load'ed, ZNODE sentinel. Concurrency-saturated (R13/R14/R15 all
// regressed): gather is memory-system (L3/fabric random-access) bound.
// z split bf16 hi/lo -> LDS [node][k] stride 72. MLP: per wave 16 nodes x 64
// feats via mfma_f32_16x16x32_bf16, 3-product split, W pre-packed B-frags.
template <bool RESID>
__global__ __launch_bounds__(256, 6)
void conv_kernel(const unsigned short* __restrict__ hin, unsigned short* __restrict__ hout,
                 const int* __restrict__ cnt, const int* __restrict__ csr,
                 const unsigned short* __restrict__ Wpk,   // layer: W1 hi|lo, W2 hi|lo
                 const float* __restrict__ b1, const float* __restrict__ b2,
                 const float* __restrict__ gam, const float* __restrict__ bet,
                 const float* __restrict__ rm, const float* __restrict__ rv) {
  __shared__ __align__(16) unsigned short zb0[64][72];   // hi
  __shared__ __align__(16) unsigned short zb1[64][72];   // lo
  const int t   = threadIdx.x;
  const int ln  = t & 63;
  const int wid = __builtin_amdgcn_readfirstlane(t >> 6);   // 0..3
  const int lc  = ln & 31;
  const bool hiH = ln >= 32;
  const int nb  = blockIdx.x * 64;
  const unsigned* hb = (const unsigned*)hin;   // row stride 32 words

  // ---- gather: wave wid -> local nodes [16*wid, 16*wid+16), 8 pairs ----
  for (int p = 0; p < 8; ++p) {
    int m = wid * 16 + 2 * p;
    int nA = nb + m; if (nA > ZNODE) nA = ZNODE;
    int nB = nA + 1; if (nB > ZNODE) nB = ZNODE;
    const int* rA = csr + (size_t)nA * CAP;
    const int* rB = csr + (size_t)nB * CAP;
    int4 a0 = *(const int4*)(rA + 0), a1q = *(const int4*)(rA + 4);
    int4 a2 = *(const int4*)(rA + 8), a3q = *(const int4*)(rA + 12);
    int4 b0 = *(const int4*)(rB + 0), b1q = *(const int4*)(rB + 4);
    int4 b2q = *(const int4*)(rB + 8), b3q = *(const int4*)(rB + 12);
    int dA = cnt[nA], dB = cnt[nB];

    int self = hiH ? nB : nA;
    float z0, z1;
    { unsigned u = hb[(size_t)self * 32 + lc]; z0 = bflo(u); z1 = bfhi(u); }
    int i0  = hiH ? b0.x  : a0.x;   int i1  = hiH ? b0.y  : a0.y;
    int i2  = hiH ? b0.z  : a0.z;   int i3  = hiH ? b0.w  : a0.w;
    int i4  = hiH ? b1q.x : a1q.x;  int i5  = hiH ? b1q.y : a1q.y;
    int i6  = hiH ? b1q.z : a1q.z;  int i7  = hiH ? b1q.w : a1q.w;
    int i8  = hiH ? b2q.x : a2.x;   int i9  = hiH ? b2q.y : a2.y;
    int i10 = hiH ? b2q.z : a2.z;   int i11 = hiH ? b2q.w : a2.w;
    int i12 = hiH ? b3q.x : a3q.x;  int i13 = hiH ? b3q.y : a3q.y;
    int i14 = hiH ? b3q.z : a3q.z;  int i15 = hiH ? b3q.w : a3q.w;
#define GACC(ix) { unsigned u = hb[(size_t)(ix) * 32 + lc]; z0 += bflo(u); z1 += bfhi(u); }
    GACC(i0)  GACC(i1)  GACC(i2)  GACC(i3)
    GACC(i4)  GACC(i5)  GACC(i6)  GACC(i7)
    GACC(i8)  GACC(i9)  GACC(i10) GACC(i11)
    GACC(i12) GACC(i13) GACC(i14) GACC(i15)
#undef GACC
    if (dA > 16 && !hiH)
      for (int q = 16; q < dA; ++q) { unsigned u = hb[(size_t)rA[q] * 32 + lc]; z0 += bflo(u); z1 += bfhi(u); }
    if (dB > 16 && hiH)
      for (int q = 16; q < dB; ++q) { unsigned u = hb[(size_t)rB[q] * 32 + lc]; z0 += bflo(u); z1 += bfhi(u); }
    int mr = m + (hiH ? 1 : 0);
    unsigned h0 = f2bf1(z0);
    float r0 = z0 - __uint_as_float(h0 << 16);
    float r1 = z1 - __uint_as_float(f2bf1(z1) << 16);
    *(unsigned*)&zb0[mr][2 * lc] = h0 | (f2bf1(z1) << 16);
    *(unsigned*)&zb1[mr][2 * lc] = f2bf1(r0) | (f2bf1(r1) << 16);
  }
  __syncthreads();    // fence: order gather LDS stores before b128 frag reads

  const int l15 = ln & 15, lg = ln >> 4;
  const int arow = 16 * wid + l15;                  // A-frag row (node-local)
  const unsigned short* W1pk = Wpk;
  const unsigned short* W2pk = Wpk + 8192;          // per-matrix block = 8192 bf16

  // ---- matvec 1: a1 = relu(z @ W1 + b1), wave-local 16 nodes x 64 feats ----
  f32x4 acc[4];
#pragma unroll
  for (int tc = 0; tc < 4; ++tc) {
    float bv = b1[tc * 16 + l15];
    acc[tc] = (f32x4){bv, bv, bv, bv};
  }
#pragma unroll
  for (int ks = 0; ks < 2; ++ks) {
    bf16x8 ah = *(const bf16x8*)&zb0[arow][lg * 8 + ks * 32];
    bf16x8 al = *(const bf16x8*)&zb1[arow][lg * 8 + ks * 32];
#pragma unroll
    for (int tc = 0; tc < 4; ++tc) {
      bf16x8 bh = *(const bf16x8*)&W1pk[(size_t)((tc * 2 + ks) * 64 + ln) * 8];
      bf16x8 bl = *(const bf16x8*)&W1pk[4096 + (size_t)((tc * 2 + ks) * 64 + ln) * 8];
      acc[tc] = __builtin_amdgcn_mfma_f32_16x16x32_bf16(ah, bh, acc[tc], 0, 0, 0);
      acc[tc] = __builtin_amdgcn_mfma_f32_16x16x32_bf16(al, bh, acc[tc], 0, 0, 0);
      acc[tc] = __builtin_amdgcn_mfma_f32_16x16x32_bf16(ah, bl, acc[tc], 0, 0, 0);
    }
  }
  __syncthreads();    // all matvec-1 A reads complete before a1 overwrite

  // ---- ReLU + split + write a1 back to zb (same wave-private rows) ----
#pragma unroll
  for (int tc = 0; tc < 4; ++tc) {
#pragma unroll
    for (int r = 0; r < 4; ++r) {
      float v = fmaxf(acc[tc][r], 0.0f);
      int node = 16 * wid + lg * 4 + r;
      int feat = tc * 16 + l15;
      unsigned short hh = (unsigned short)f2bf1(v);
      zb0[node][feat] = hh;
      zb1[node][feat] = (unsigned short)f2bf1(v - bf2f(hh));
    }
  }
  __syncthreads();    // fence: order a1 stores before matvec-2 frag reads

  // ---- matvec 2: y = a1 @ W2 + b2 ----
#pragma unroll
  for (int tc = 0; tc < 4; ++tc) {
    float bv = b2[tc * 16 + l15];
    acc[tc] = (f32x4){bv, bv, bv, bv};
  }
#pragma unroll
  for (int ks = 0; ks < 2; ++ks) {
    bf16x8 ah = *(const bf16x8*)&zb0[arow][lg * 8 + ks * 32];
    bf16x8 al = *(const bf16x8*)&zb1[arow][lg * 8 + ks * 32];
#pragma unroll
    for (int tc = 0; tc < 4; ++tc) {
      bf16x8 bh = *(const bf16x8*)&W2pk[(size_t)((tc * 2 + ks) * 64 + ln) * 8];
      bf16x8 bl = *(const bf16x8*)&W2pk[4096 + (size_t)((tc * 2 + ks) * 64 + ln) * 8];
      acc[tc] = __builtin_amdgcn_mfma_f32_16x16x32_bf16(ah, bh, acc[tc], 0, 0, 0);
      acc[tc] = __builtin_amdgcn_mfma_f32_16x16x32_bf16(al, bh, acc[tc], 0, 0, 0);
      acc[tc] = __builtin_amdgcn_mfma_f32_16x16x32_bf16(ah, bl, acc[tc], 0, 0, 0);
    }
  }

  // ---- ReLU + BN (+residual) + bf16 store ----
#pragma unroll
  for (int tc = 0; tc < 4; ++tc) {
    int feat = tc * 16 + l15;
    float sc = gam[feat] * rsqrtf(rv[feat] + 1e-5f);
    float sh = bet[feat] - rm[feat] * sc;
#pragma unroll
    for (int r = 0; r < 4; ++r) {
      int gn = nb + 16 * wid + lg * 4 + r;
      bool v = gn < N_NODES;
      int gnc = v ? gn : ZNODE;
      float y = fmaxf(acc[tc][r], 0.0f) * sc + sh;
      if (RESID) y += bf2f(hin[(size_t)gnc * 64 + feat]);
      if (v) hout[(size_t)gn * 64 + feat] = (unsigned short)f2bf1(y);
    }
  }
}

// ---------------- fused head + mean-pool partial sums (R9-proven) ----------
__global__ __launch_bounds__(512, 6)
void head_pool_kernel(const unsigned short* __restrict__ hin, float* __restrict__ out,
                      const int* __restrict__ batch,
                      const float* __restrict__ W, const float* __restrict__ b) {
  const int t   = threadIdx.x;
  const int ln  = t & 63;
  const int wid = __builtin_amdgcn_readfirstlane(t >> 6);
  const int n = blockIdx.x * 64 + ln;
  const bool valid = n < N_NODES;
  const int nn = valid ? n : ZNODE;
  const unsigned* hb = (const unsigned*)hin;

  unsigned zp[32];
#pragma unroll
  for (int cc = 0; cc < 8; ++cc) {
    uint4 u = *(const uint4*)&hb[(size_t)nn * 32 + cc * 4];
    zp[cc * 4 + 0] = u.x; zp[cc * 4 + 1] = u.y;
    zp[cc * 4 + 2] = u.z; zp[cc * 4 + 3] = u.w;
  }

  const float* Wp = W + wid * 8;
  const float* bp = b + wid * 8;
  float acc[8];
#pragma unroll
  for (int f = 0; f < 8; ++f) acc[f] = bp[f];
#pragma unroll
  for (int w = 0; w < 32; ++w) {
    float zlo = bflo(zp[w]), zhi = bfhi(zp[w]);
#pragma unroll
    for (int f = 0; f < 8; ++f) acc[f] = fmaf(zlo, Wp[(2 * w) * 64 + f], acc[f]);
#pragma unroll
    for (int f = 0; f < 8; ++f) acc[f] = fmaf(zhi, Wp[(2 * w + 1) * 64 + f], acc[f]);
  }
#pragma unroll
  for (int f = 0; f < 8; ++f) acc[f] = tanh_fast(acc[f]);

  int bg = valid ? batch[n] : -1;
  int gmax = bg;
#pragma unroll
  for (int off = 32; off >= 1; off >>= 1) gmax = max(gmax, __shfl_xor(gmax, off));
  gmax = __builtin_amdgcn_readfirstlane(gmax);
  int g0 = __builtin_amdgcn_readfirstlane(bg);

  for (int g = g0; g <= gmax; ++g) {
    float s[8];
    bool inG = (bg == g);
#pragma unroll
    for (int f = 0; f < 8; ++f) s[f] = inG ? acc[f] : 0.0f;
#pragma unroll
    for (int off = 1; off <= 32; off <<= 1) {
#pragma unroll
      for (int f = 0; f < 8; ++f) s[f] += __shfl_xor(s[f], off);
    }
    float sv = s[0];
    sv = (ln == 1) ? s[1] : sv;  sv = (ln == 2) ? s[2] : sv;
    sv = (ln == 3) ? s[3] : sv;  sv = (ln == 4) ? s[4] : sv;
    sv = (ln == 5) ? s[5] : sv;  sv = (ln == 6) ? s[6] : sv;
    sv = (ln == 7) ? s[7] : sv;
    if (ln < 8) atomicAdd(&out[g * 64 + wid * 8 + ln], sv);
  }
}

// out[g][f] /= max(count_g, 1)
__global__ void div_kernel(float* __restrict__ out, const int* __restrict__ goff) {
  int i = blockIdx.x * blockDim.x + threadIdx.x;
  if (i >= N_GRAPHS * 64) return;
  int g = i >> 6;
  int c = goff[g + 1] - goff[g];
  out[i] /= (float)max(c, 1);
}

// ---------------- launch ----------------
extern "C" void kernel_launch(void* const* d_in, const int* in_sizes, int n_in,
                              void* d_out, int out_size, void* d_ws, size_t ws_size,
                              hipStream_t stream) {
  const float* x     = (const float*)d_in[0];
  const int*   ei    = (const int*)d_in[1];
  const int*   batch = (const int*)d_in[2];
  const float* c1_W1 = (const float*)d_in[3];
  const float* c1_b1 = (const float*)d_in[4];
  const float* c1_W2 = (const float*)d_in[5];
  const float* c1_b2 = (const float*)d_in[6];
  const float* c1_g  = (const float*)d_in[7];
  const float* c1_be = (const float*)d_in[8];
  const float* c1_m  = (const float*)d_in[9];
  const float* c1_v  = (const float*)d_in[10];
  const float* cs_W1 = (const float*)d_in[11];
  const float* cs_b1 = (const float*)d_in[12];
  const float* cs_W2 = (const float*)d_in[13];
  const float* cs_b2 = (const float*)d_in[14];
  const float* cs_g  = (const float*)d_in[15];
  const float* cs_be = (const float*)d_in[16];
  const float* cs_m  = (const float*)d_in[17];
  const float* cs_v  = (const float*)d_in[18];
  const float* lin_W = (const float*)d_in[19];
  const float* lin_b = (const float*)d_in[20];
  float* out = (float*)d_out;

  size_t cur = 0;
  auto take = [&](size_t bytes) -> void* {
    void* p = (char*)d_ws + cur;
    cur += (bytes + 255) & ~(size_t)255;
    return p;
  };
  int* cnt  = (int*)take((N_NODES + 1) * sizeof(int));
  size_t zbytes = cur;                       // cnt zeroed every call
  int* goff = (int*)take((N_GRAPHS + 1) * sizeof(int));
  int* csr  = (int*)take((size_t)(N_NODES + 1) * CAP * sizeof(int));
  unsigned short* bufA = (unsigned short*)take((size_t)(N_NODES + 1) * HDIM * sizeof(unsigned short));
  unsigned short* bufB = (unsigned short*)take((size_t)(N_NODES + 1) * HDIM * sizeof(unsigned short));
  unsigned short* wpk  = (unsigned short*)take((size_t)10 * 8192 * sizeof(unsigned short));
  (void)ws_size; (void)in_sizes; (void)n_in; (void)out_size;

  hipMemsetAsync(cnt, 0, zbytes, stream);
  hipMemsetAsync(bufA + (size_t)ZNODE * HDIM, 0, HDIM * sizeof(unsigned short), stream);
  hipMemsetAsync(out, 0, N_GRAPHS * 64 * sizeof(float), stream);

  // merged prep (prefill + cvt_pad + packw + goff), then fill
  prep_kernel<<<2048, 256, 0, stream>>>(x, bufB, csr, batch, goff,
                                        c1_W1, c1_W2, cs_W1, cs_W2, wpk);
  fill_kernel<<<RNG * CHUNKS, 256, 0, stream>>>(ei, cnt, csr);

  const int NBLK = (N_NODES + 63) / 64;      // 1563 blocks x 256 thr (4 waves)

  // conv1: bufB(x) -> bufA  (layer l weight block at wpk + l*16384)
  conv_kernel<false><<<NBLK, 256, 0, stream>>>(bufB, bufA, cnt, csr,
      wpk, c1_b1, c1_b2, c1_g, c1_be, c1_m, c1_v);

  // 4 residual convs: A->B->A->B->A
  unsigned short* srcp = bufA;
  unsigned short* dstp = bufB;
  for (int l = 0; l < N_RES; ++l) {
    conv_kernel<true><<<NBLK, 256, 0, stream>>>(srcp, dstp, cnt, csr,
        wpk + (size_t)(l + 1) * 16384,
        cs_b1 + l * 64, cs_b2 + l * 64,
        cs_g + l * 64, cs_be + l * 64, cs_m + l * 64, cs_v + l * 64);
    unsigned short* tmp = srcp; srcp = dstp; dstp = tmp;
  }
  // final h in bufA (srcp); fused head + pool -> out, then divide by counts
  head_pool_kernel<<<NBLK, 512, 0, stream>>>(srcp, out, batch, lin_W, lin_b);
  div_kernel<<<(N_GRAPHS * 64 + 255) / 256, 256, 0, stream>>>(out, goff);
}